// Round 2
// baseline (363.156 us; speedup 1.0000x reference)
//
#include <hip/hip_runtime.h>
#include <hip/hip_bf16.h>

#define M_DIM 64
#define K_DIM 4096
#define N_DIM 14336
#define KSPLIT 16
#define KSLICE (K_DIM / KSPLIT)  // 256
#define NB_BLK 256               // n columns per block (4 waves x 64)
#define NBLKS (N_DIM / NB_BLK)   // 56
#define CHUNKS (KSLICE / 32)     // 8

typedef __attribute__((ext_vector_type(8))) short bf16x8;
typedef __attribute__((ext_vector_type(4))) float f32x4;

// ---------------------------------------------------------------------------
// prep: split x (fp32) into bf16 hi/lo, stored in MFMA-A-fragment layout:
// elem idx = (k/8)*(64*8) + m*8 + (k%8).
// Thread mapping: lanes sweep kb (coalesced 2KB/wave reads of one x row).
__global__ void prep_split(const float* __restrict__ x,
                           __hip_bfloat16* __restrict__ xh,
                           __hip_bfloat16* __restrict__ xl) {
  int tg = blockIdx.x * blockDim.x + threadIdx.x;  // 0..32767
  int kb = tg & 511;
  int m = tg >> 9;
  const float* xp = x + m * K_DIM + kb * 8;
  unsigned short hs[8], ls[8];
#pragma unroll
  for (int j = 0; j < 8; ++j) {
    float v = xp[j];
    unsigned hv = __float_as_uint(v) & 0xFFFF0000u;  // bf16 truncate
    float r = v - __uint_as_float(hv);
    hs[j] = (unsigned short)(hv >> 16);
    ls[j] = (unsigned short)(__float_as_uint(r) >> 16);  // exact-ish tail
  }
  int o = kb * (M_DIM * 8) + m * 8;
  *(uint4*)((unsigned short*)xh + o) = *(uint4*)hs;
  *(uint4*)((unsigned short*)xl + o) = *(uint4*)ls;
}

// rowsum(x) per row m (for the offset term)
__global__ void rowsum_k(const float* __restrict__ x, float* __restrict__ rs) {
  int m = blockIdx.x;
  int t = threadIdx.x;
  float s = 0.f;
  for (int k = t; k < K_DIM; k += 256) s += x[m * K_DIM + k];
#pragma unroll
  for (int off = 32; off > 0; off >>= 1) s += __shfl_down(s, off, 64);
  __shared__ float red[4];
  if ((t & 63) == 0) red[t >> 6] = s;
  __syncthreads();
  if (t == 0) rs[m] = red[0] + red[1] + red[2] + red[3];
}

__global__ void zero_out(float* __restrict__ out) {
  int i = blockIdx.x * blockDim.x + threadIdx.x;  // 229376 float4s
  ((float4*)out)[i] = make_float4(0.f, 0.f, 0.f, 0.f);
}

// ---------------------------------------------------------------------------
// Barrier-free streaming GEMM. Block: 4 waves, each wave owns 64 n-columns,
// all 64 m rows, k-range KSLICE. W loads go straight to B-fragments (per-lane
// dwords; 4 n-frags/wave -> full 128B line use). A (x hi/lo) staged once into
// LDS (one barrier). Partial results combined via HW fp32 atomics.
__global__ __launch_bounds__(256) void wqmm(
    const int* __restrict__ W, const __hip_bfloat16* __restrict__ xh,
    const __hip_bfloat16* __restrict__ xl, const float* __restrict__ rowsum,
    const float* __restrict__ scale, const float* __restrict__ offset,
    const float* __restrict__ bias, float* __restrict__ out) {
  // ash[h][kbrel][m*8 + j] : 2 * 32 * 512 ushort = 64 KB
  __shared__ __align__(16) unsigned short ash[2][KSLICE / 8][M_DIM * 8];

  const int t = threadIdx.x;
  const int lane = t & 63;
  const int wv = t >> 6;
  const int quad = lane >> 4;
  const int lnk = lane & 15;
  const int nb = blockIdx.x % NBLKS;
  const int ks = blockIdx.x / NBLKS;
  const int k0 = ks * KSLICE;
  const int nbase = nb * NB_BLK + wv * 64;

  // stage A slice (layout-preserving linear copy: slice starts at elem k0*64)
  {
    const uint4* srch = (const uint4*)((const unsigned short*)xh + k0 * 64);
    const uint4* srcl = (const uint4*)((const unsigned short*)xl + k0 * 64);
    uint4* dsth = (uint4*)&ash[0][0][0];
    uint4* dstl = (uint4*)&ash[1][0][0];
#pragma unroll
    for (int i = 0; i < 8; ++i) {  // 32KB per array / 16B / 256 thr = 8
      dsth[t + i * 256] = srch[t + i * 256];
      dstl[t + i * 256] = srcl[t + i * 256];
    }
  }
  __syncthreads();

  f32x4 acc[4][4] = {};  // [m-tile][n-frag]

  const int* wp = W + (size_t)(k0 + quad * 8) * N_DIM + nbase + lnk;

#pragma unroll 2
  for (int c = 0; c < CHUNKS; ++c) {
    // B: 32 per-lane dword loads (8 k-rows x 4 n-frags)
    int raw[4][8];
#pragma unroll
    for (int j = 0; j < 8; ++j) {
      const int* pj = wp + (size_t)(c * 32 + j) * N_DIM;
#pragma unroll
      for (int f = 0; f < 4; ++f) raw[f][j] = pj[f * 16];
    }
    // int -> bf16 pack (exact: |w| <= 128)
    bf16x8 bfr[4];
#pragma unroll
    for (int f = 0; f < 4; ++f) {
      union { int i4[4]; bf16x8 v; } u;
#pragma unroll
      for (int wd = 0; wd < 4; ++wd) {
        unsigned lo = __float_as_uint((float)raw[f][2 * wd]);
        unsigned hi = __float_as_uint((float)raw[f][2 * wd + 1]);
        u.i4[wd] = (int)((lo >> 16) | (hi & 0xFFFF0000u));
      }
      bfr[f] = u.v;
    }
    // A fragments from LDS + MFMA
#pragma unroll
    for (int mt = 0; mt < 4; ++mt) {
      bf16x8 ah = *(const bf16x8*)&ash[0][c * 4 + quad][(mt * 16 + lnk) * 8];
      bf16x8 al = *(const bf16x8*)&ash[1][c * 4 + quad][(mt * 16 + lnk) * 8];
#pragma unroll
      for (int f = 0; f < 4; ++f) {
        acc[mt][f] =
            __builtin_amdgcn_mfma_f32_16x16x32_bf16(ah, bfr[f], acc[mt][f], 0, 0, 0);
        acc[mt][f] =
            __builtin_amdgcn_mfma_f32_16x16x32_bf16(al, bfr[f], acc[mt][f], 0, 0, 0);
      }
    }
  }

  // epilogue: atomically add scale*acc (+ affine term once, on k-slice 0)
  const int mb = quad * 4;  // C/D: col = lane&15 (n), row = quad*4 + reg (m)
#pragma unroll
  for (int f = 0; f < 4; ++f) {
    int n = nbase + f * 16 + lnk;
    float s = scale[n];
    float so = s * offset[n];
    float bi = bias[n];
#pragma unroll
    for (int mt = 0; mt < 4; ++mt) {
#pragma unroll
      for (int r = 0; r < 4; ++r) {
        int m = mt * 16 + mb + r;
        float v = acc[mt][f][r] * s;
        if (ks == 0) v += so * rowsum[m] + bi;
        unsafeAtomicAdd(out + (size_t)m * N_DIM + n, v);
      }
    }
  }
}

extern "C" void kernel_launch(void* const* d_in, const int* in_sizes, int n_in,
                              void* d_out, int out_size, void* d_ws,
                              size_t ws_size, hipStream_t stream) {
  const float* x = (const float*)d_in[0];
  const int* W = (const int*)d_in[1];
  const float* scale = (const float*)d_in[2];
  const float* offset = (const float*)d_in[3];
  const float* bias = (const float*)d_in[4];
  float* out = (float*)d_out;

  __hip_bfloat16* xh = (__hip_bfloat16*)d_ws;
  __hip_bfloat16* xl = xh + (size_t)M_DIM * K_DIM;
  float* rowsum = (float*)(xl + (size_t)M_DIM * K_DIM);

  zero_out<<<M_DIM * N_DIM / 4 / 256, 256, 0, stream>>>(out);
  prep_split<<<128, 256, 0, stream>>>(x, xh, xl);
  rowsum_k<<<64, 256, 0, stream>>>(x, rowsum);
  wqmm<<<NBLKS * KSPLIT, 256, 0, stream>>>(W, xh, xl, rowsum, scale, offset,
                                           bias, out);
}